// Round 4
// baseline (151.005 us; speedup 1.0000x reference)
//
#include <hip/hip_runtime.h>
#include <hip/hip_bf16.h>

typedef __attribute__((ext_vector_type(8))) short bf16x8;
typedef __attribute__((ext_vector_type(4))) float f32x4;

#define N_IN  128
#define N_HID 64
#define LDS_PAD 10     // bf16 pad -> row stride 138 shorts = 69 dwords (odd*? 69 mod 32 = 5, invertible) -> conflict-free fragment reads
#define TPB 256
#define WAVES_PER_BLOCK 4

// 4-op round-to-nearest-even f32->bf16. Inputs are finite (Gaussian data),
// so skip the NaN branch that __float2bfloat16 carries.
static __device__ inline short f2bf(float f) {
    unsigned u = __float_as_uint(f);
    u += 0x7fffu + ((u >> 16) & 1u);
    return (short)(u >> 16);
}

__global__ __launch_bounds__(TPB, 4)   // cap VGPR at 128 -> 4 waves/SIMD
void atomwise_mfma_kernel(const float* __restrict__ x,
                          const float* __restrict__ W1,
                          const float* __restrict__ b1,
                          const float* __restrict__ W2,
                          const float* __restrict__ b2,
                          const int*   __restrict__ idx_m,
                          float*       __restrict__ out,
                          int n_atoms)
{
    __shared__ short w1t[N_HID][N_IN + LDS_PAD];   // W1^T in bf16

    const int tid = threadIdx.x;

    // ---- one-time: stage W1^T (bf16) into LDS. W1 is [128][64] row-major ----
    for (int e = tid; e < N_IN * N_HID; e += TPB) {
        int k = e >> 6;     // 0..127
        int n = e & 63;     // 0..63
        w1t[n][k] = f2bf(W1[e]);
    }
    __syncthreads();

    const int lane = tid & 63;
    const int wv   = tid >> 6;
    const int l15  = lane & 15;
    const int g    = lane >> 4;     // 0..3 (k-group; also selects atoms g*4..g*4+3)

    // per-lane channel constants: channel = nt*16 + l15
    float bb[4], w2v[4];
    #pragma unroll
    for (int nt = 0; nt < 4; ++nt) {
        bb[nt]  = b1[nt * 16 + l15];
        w2v[nt] = W2[nt * 16 + l15];
    }
    const float b2v = b2[0];

    // per-lane LDS row base for B fragments: row = nt*16 + l15, col = kt*32 + g*8
    const short* wrow = &w1t[l15][g * 8];

    const int n_tiles = (n_atoms + 15) >> 4;
    const int n_waves = gridDim.x * WAVES_PER_BLOCK;
    int tile = blockIdx.x * WAVES_PER_BLOCK + wv;
    if (tile >= n_tiles) return;

    // ---- prologue: issue loads for first tile ----
    f32x4 xf[8];
    int mv;     // idx_m for atom (tile*16 + l15), clamped
    {
        int row  = tile * 16 + l15;
        int rowc = row < n_atoms ? row : (n_atoms - 1);
        const float* xp = x + (size_t)rowc * N_IN + g * 8;
        #pragma unroll
        for (int kt = 0; kt < 4; ++kt) {
            xf[2 * kt]     = *reinterpret_cast<const f32x4*>(xp + kt * 32);
            xf[2 * kt + 1] = *reinterpret_cast<const f32x4*>(xp + kt * 32 + 4);
        }
        mv = idx_m[rowc];
    }

    while (true) {
        // ---- convert current tile to bf16 A-fragments (waits vmcnt on its loads) ----
        bf16x8 a[4];
        #pragma unroll
        for (int kt = 0; kt < 4; ++kt) {
            f32x4 lo = xf[2 * kt];
            f32x4 hi = xf[2 * kt + 1];
            bf16x8 t;
            t[0] = f2bf(lo[0]); t[1] = f2bf(lo[1]);
            t[2] = f2bf(lo[2]); t[3] = f2bf(lo[3]);
            t[4] = f2bf(hi[0]); t[5] = f2bf(hi[1]);
            t[6] = f2bf(hi[2]); t[7] = f2bf(hi[3]);
            a[kt] = t;
        }

        // ---- prefetch next tile's x + idx into the (now free) buffers ----
        const int  ntile     = tile + n_waves;
        const bool have_next = ntile < n_tiles;
        int nmv = 0;
        if (have_next) {            // wave-uniform branch; loop backedge only from here
            int row  = ntile * 16 + l15;
            int rowc = row < n_atoms ? row : (n_atoms - 1);
            const float* xp = x + (size_t)rowc * N_IN + g * 8;
            #pragma unroll
            for (int kt = 0; kt < 4; ++kt) {
                xf[2 * kt]     = *reinterpret_cast<const f32x4*>(xp + kt * 32);
                xf[2 * kt + 1] = *reinterpret_cast<const f32x4*>(xp + kt * 32 + 4);
            }
            nmv = idx_m[rowc];
        }

        // ---- MFMA: 16 atoms x 64 hid over K=128; B fragments re-read from LDS
        //      each iteration (frees ~64 VGPRs vs register-resident bfrag).
        //      Launder the base pointer so LICM can't hoist the 16 ds_reads. ----
        const short* wb = wrow;
        asm volatile("" : "+v"(wb));
        f32x4 acc[4] = {};          // [nt]; rows g*4+j, col l15
        #pragma unroll
        for (int kt = 0; kt < 4; ++kt) {
            #pragma unroll
            for (int nt = 0; nt < 4; ++nt) {
                const short* p = wb + (size_t)nt * 16 * (N_IN + LDS_PAD) + kt * 32;
                bf16x8 bfrag = *reinterpret_cast<const bf16x8*>(p);
                acc[nt] = __builtin_amdgcn_mfma_f32_16x16x32_bf16(
                              a[kt], bfrag, acc[nt], 0, 0, 0);
            }
        }

        // ---- epilogue: bias + silu + dot(W2) ----
        float p[4];
        #pragma unroll
        for (int j = 0; j < 4; ++j) {
            float s = 0.f;
            #pragma unroll
            for (int nt = 0; nt < 4; ++nt) {
                float z = acc[nt][j] + bb[nt];
                float h = z / (1.f + __expf(-z));   // silu
                s += h * w2v[nt];
            }
            p[j] = s;
        }

        // ---- segment reduction: fast path when the whole tile is one molecule ----
        const int  first = __shfl(mv, 0);
        const bool full  = (tile * 16 + 16) <= n_atoms;
        const bool uni   = full && (__all(mv == first) != 0);

        if (uni) {
            // all 16 atoms -> one molecule: one wave-wide sum, one atomic
            float s = p[0] + p[1] + p[2] + p[3];
            #pragma unroll
            for (int m = 1; m < 64; m <<= 1)
                s += __shfl_xor(s, m, 64);
            if (lane == 0)
                atomicAdd(&out[first], s + 16.0f * b2v);
        } else {
            // gather per-atom molecule ids before any further reduction
            int ia[4];
            #pragma unroll
            for (int j = 0; j < 4; ++j)
                ia[j] = __shfl(mv, g * 4 + j);
            // reduce across the 16 lanes sharing g (channels 0..63)
            #pragma unroll
            for (int m = 1; m < 16; m <<= 1) {
                #pragma unroll
                for (int j = 0; j < 4; ++j)
                    p[j] += __shfl_xor(p[j], m, 64);
            }
            if (l15 == 0) {
                #pragma unroll
                for (int j = 0; j < 4; ++j) {
                    int atom = tile * 16 + g * 4 + j;
                    if (atom < n_atoms)
                        atomicAdd(&out[ia[j]], p[j] + b2v);
                }
            }
        }

        if (!have_next) break;
        tile = ntile;
        mv   = nmv;
    }
}

extern "C" void kernel_launch(void* const* d_in, const int* in_sizes, int n_in,
                              void* d_out, int out_size, void* d_ws, size_t ws_size,
                              hipStream_t stream) {
    const float* x   = (const float*)d_in[0];
    const float* W1  = (const float*)d_in[1];
    const float* b1  = (const float*)d_in[2];
    const float* W2  = (const float*)d_in[3];
    const float* b2  = (const float*)d_in[4];
    const int*   idx = (const int*)d_in[5];
    // d_in[6] = num_segments (scalar) — equals out_size

    const int n_atoms = in_sizes[0] / N_IN;
    float* out = (float*)d_out;

    hipMemsetAsync(d_out, 0, (size_t)out_size * sizeof(float), stream);

    const int blocks = 2048;
    atomwise_mfma_kernel<<<blocks, TPB, 0, stream>>>(
        x, W1, b1, W2, b2, idx, out, n_atoms);
}

// Round 5
// 129.598 us; speedup vs baseline: 1.1652x; 1.1652x over previous
//
#include <hip/hip_runtime.h>
#include <hip/hip_bf16.h>

typedef __attribute__((ext_vector_type(8))) short bf16x8;
typedef __attribute__((ext_vector_type(4))) float f32x4;

#define N_IN  128
#define N_HID 64
#define LDS_PAD 8      // bf16 elements of pad per row
#define TPB 256
#define WAVES_PER_BLOCK 4

// 4-op round-to-nearest-even f32->bf16. Inputs are finite (Gaussian data),
// so skip the NaN branch that __float2bfloat16 carries.
static __device__ inline short f2bf(float f) {
    unsigned u = __float_as_uint(f);
    u += 0x7fffu + ((u >> 16) & 1u);
    return (short)(u >> 16);
}

__global__ __launch_bounds__(TPB, 3)
void atomwise_mfma_kernel(const float* __restrict__ x,
                          const float* __restrict__ W1,
                          const float* __restrict__ b1,
                          const float* __restrict__ W2,
                          const float* __restrict__ b2,
                          const int*   __restrict__ idx_m,
                          float*       __restrict__ out,
                          int n_atoms)
{
    __shared__ short w1t[N_HID][N_IN + LDS_PAD];   // W1^T in bf16

    const int tid = threadIdx.x;

    // ---- one-time: stage W1^T (bf16) into LDS. W1 is [128][64] row-major ----
    for (int e = tid; e < N_IN * N_HID; e += TPB) {
        int k = e >> 6;     // 0..127
        int n = e & 63;     // 0..63
        w1t[n][k] = f2bf(W1[e]);
    }
    __syncthreads();

    const int lane = tid & 63;
    const int wv   = tid >> 6;
    const int l15  = lane & 15;
    const int g    = lane >> 4;     // 0..3 (k-group; also selects atoms g*4..g*4+3)

    // ---- hoist full B operand (W1^T fragments) into registers ----
    bf16x8 bfrag[4][4];             // [kt][nt]
    #pragma unroll
    for (int kt = 0; kt < 4; ++kt)
        #pragma unroll
        for (int nt = 0; nt < 4; ++nt) {
            const short* p = &w1t[nt * 16 + l15][kt * 32 + g * 8];
            bfrag[kt][nt] = *reinterpret_cast<const bf16x8*>(p);
        }

    // per-lane channel constants: channel = nt*16 + l15
    float bb[4], w2v[4];
    #pragma unroll
    for (int nt = 0; nt < 4; ++nt) {
        bb[nt]  = b1[nt * 16 + l15];
        w2v[nt] = W2[nt * 16 + l15];
    }
    const float b2v = b2[0];

    const int n_tiles = (n_atoms + 15) >> 4;
    const int n_waves = gridDim.x * WAVES_PER_BLOCK;
    int tile = blockIdx.x * WAVES_PER_BLOCK + wv;
    if (tile >= n_tiles) return;

    // ---- prologue: issue loads for first tile ----
    f32x4 xf[8];
    int mv;     // idx_m for atom (tile*16 + l15), clamped
    {
        int row  = tile * 16 + l15;
        int rowc = row < n_atoms ? row : (n_atoms - 1);
        const float* xp = x + (size_t)rowc * N_IN + g * 8;
        #pragma unroll
        for (int kt = 0; kt < 4; ++kt) {
            xf[2 * kt]     = *reinterpret_cast<const f32x4*>(xp + kt * 32);
            xf[2 * kt + 1] = *reinterpret_cast<const f32x4*>(xp + kt * 32 + 4);
        }
        mv = idx_m[rowc];
        // dummy no-op atomic so the loop-entry VMEM trail (loads, idx, atomic)
        // matches the backedge exactly -> waitcnt pass can prove vmcnt(2) at the
        // convert and never waits on an atomic completion.
        if (lane == 0)
            atomicAdd(&out[mv], 0.0f);
    }

    while (true) {
        // ---- convert current tile to bf16 A-fragments (waits vmcnt on its loads) ----
        bf16x8 a[4];
        #pragma unroll
        for (int kt = 0; kt < 4; ++kt) {
            f32x4 lo = xf[2 * kt];
            f32x4 hi = xf[2 * kt + 1];
            bf16x8 t;
            t[0] = f2bf(lo[0]); t[1] = f2bf(lo[1]);
            t[2] = f2bf(lo[2]); t[3] = f2bf(lo[3]);
            t[4] = f2bf(hi[0]); t[5] = f2bf(hi[1]);
            t[6] = f2bf(hi[2]); t[7] = f2bf(hi[3]);
            a[kt] = t;
        }

        // ---- prefetch next tile's x + idx into the (now free) buffers ----
        const int  ntile     = tile + n_waves;
        const bool have_next = ntile < n_tiles;
        int nmv = 0;
        if (have_next) {            // wave-uniform branch; loop backedge only from here
            int row  = ntile * 16 + l15;
            int rowc = row < n_atoms ? row : (n_atoms - 1);
            const float* xp = x + (size_t)rowc * N_IN + g * 8;
            #pragma unroll
            for (int kt = 0; kt < 4; ++kt) {
                xf[2 * kt]     = *reinterpret_cast<const f32x4*>(xp + kt * 32);
                xf[2 * kt + 1] = *reinterpret_cast<const f32x4*>(xp + kt * 32 + 4);
            }
            nmv = idx_m[rowc];
        }

        // ---- MFMA: 16 atoms x 64 hid over K=128 ----
        f32x4 acc[4] = {};          // [nt]; rows g*4+j, col l15
        #pragma unroll
        for (int kt = 0; kt < 4; ++kt)
            #pragma unroll
            for (int nt = 0; nt < 4; ++nt)
                acc[nt] = __builtin_amdgcn_mfma_f32_16x16x32_bf16(
                              a[kt], bfrag[kt][nt], acc[nt], 0, 0, 0);

        // ---- epilogue: bias + silu + dot(W2) ----
        float p[4];
        #pragma unroll
        for (int j = 0; j < 4; ++j) {
            float s = 0.f;
            #pragma unroll
            for (int nt = 0; nt < 4; ++nt) {
                float z = acc[nt][j] + bb[nt];
                float h = z / (1.f + __expf(-z));   // silu
                s += h * w2v[nt];
            }
            p[j] = s;
        }

        // ---- segment reduction: fast path when the whole tile is one molecule.
        //      Both paths issue EXACTLY ONE atomic instruction (uniform VMEM trail). ----
        const int  first = __shfl(mv, 0);
        const bool full  = (tile * 16 + 16) <= n_atoms;
        const bool uni   = full && (__all(mv == first) != 0);

        if (uni) {
            // all 16 atoms -> one molecule: one wave-wide sum, one atomic
            float s = p[0] + p[1] + p[2] + p[3];
            #pragma unroll
            for (int m = 1; m < 64; m <<= 1)
                s += __shfl_xor(s, m, 64);
            if (lane == 0)
                atomicAdd(&out[first], s + 16.0f * b2v);
        } else {
            // molecule ids of this group's 4 atoms (broadcast to all lanes)
            int ia0 = __shfl(mv, g * 4 + 0);
            int ia1 = __shfl(mv, g * 4 + 1);
            int ia2 = __shfl(mv, g * 4 + 2);
            int ia3 = __shfl(mv, g * 4 + 3);
            // allreduce across the 16 lanes sharing g (sums channels over l15)
            #pragma unroll
            for (int m = 1; m < 16; m <<= 1) {
                #pragma unroll
                for (int j = 0; j < 4; ++j)
                    p[j] += __shfl_xor(p[j], m, 64);
            }
            // register-local inclusive scan by molecule id over the group's 4 atoms
            // (ids sorted -> contiguous runs); run-end lanes fire ONE masked atomic.
            const int a0 = tile * 16 + g * 4;
            float v0 = p[0] + b2v;
            float v1 = p[1] + b2v + ((ia0 == ia1) ? v0 : 0.f);
            float v2 = p[2] + b2v + ((ia1 == ia2) ? v1 : 0.f);
            float v3 = p[3] + b2v + ((ia2 == ia3) ? v2 : 0.f);
            bool  l0 = (ia0 != ia1) || (a0 + 1 >= n_atoms);
            bool  l1 = (ia1 != ia2) || (a0 + 2 >= n_atoms);
            bool  l2 = (ia2 != ia3) || (a0 + 3 >= n_atoms);
            // lane j = l15 (<4) of each group handles the run ending at atom a0+j
            float v    = (l15 == 0) ? v0  : (l15 == 1) ? v1  : (l15 == 2) ? v2  : v3;
            int   myia = (l15 == 0) ? ia0 : (l15 == 1) ? ia1 : (l15 == 2) ? ia2 : ia3;
            bool  last = (l15 == 0) ? l0  : (l15 == 1) ? l1  : (l15 == 2) ? l2  : true;
            int   atom = a0 + l15;
            if (l15 < 4 && last && atom < n_atoms)
                atomicAdd(&out[myia], v);   // distinct runs; rare cross-group
                                            // collisions serialize inside the instr
        }

        if (!have_next) break;
        tile = ntile;
        mv   = nmv;
    }
}

extern "C" void kernel_launch(void* const* d_in, const int* in_sizes, int n_in,
                              void* d_out, int out_size, void* d_ws, size_t ws_size,
                              hipStream_t stream) {
    const float* x   = (const float*)d_in[0];
    const float* W1  = (const float*)d_in[1];
    const float* b1  = (const float*)d_in[2];
    const float* W2  = (const float*)d_in[3];
    const float* b2  = (const float*)d_in[4];
    const int*   idx = (const int*)d_in[5];
    // d_in[6] = num_segments (scalar) — equals out_size

    const int n_atoms = in_sizes[0] / N_IN;
    float* out = (float*)d_out;

    hipMemsetAsync(d_out, 0, (size_t)out_size * sizeof(float), stream);

    // 4096 blocks: halves per-block work vs 2048 -> halves the end-of-kernel
    // residency drain window (blocks stream; last-block tail ~ one block-duration)
    const int blocks = 4096;
    atomwise_mfma_kernel<<<blocks, TPB, 0, stream>>>(
        x, W1, b1, W2, b2, idx, out, n_atoms);
}

// Round 6
// 112.248 us; speedup vs baseline: 1.3453x; 1.1546x over previous
//
#include <hip/hip_runtime.h>
#include <hip/hip_bf16.h>

typedef __attribute__((ext_vector_type(8))) short bf16x8;
typedef __attribute__((ext_vector_type(4))) float f32x4;
typedef __attribute__((ext_vector_type(4))) int   i32x4;

#define N_IN  128
#define N_HID 64
#define LDS_PAD 8      // bf16 elements of pad per row
#define TPB 256
#define WAVES_PER_BLOCK 4

// scalar RNE f32->bf16 (one-time W1 staging only)
static __device__ inline short f2bf(float f) {
    unsigned u = __float_as_uint(f);
    u += 0x7fffu + ((u >> 16) & 1u);
    return (short)(u >> 16);
}

// HW packed convert: 8 f32 -> 8 bf16 in 4 VALU instructions, pre-packed.
// v_cvt_pk_bf16_f32: dst.lo16 = bf16(src0), dst.hi16 = bf16(src1).
static __device__ inline bf16x8 cvt8(f32x4 lo, f32x4 hi) {
    int i0, i1, i2, i3;
    asm("v_cvt_pk_bf16_f32 %0, %1, %2" : "=v"(i0) : "v"(lo[0]), "v"(lo[1]));
    asm("v_cvt_pk_bf16_f32 %0, %1, %2" : "=v"(i1) : "v"(lo[2]), "v"(lo[3]));
    asm("v_cvt_pk_bf16_f32 %0, %1, %2" : "=v"(i2) : "v"(hi[0]), "v"(hi[1]));
    asm("v_cvt_pk_bf16_f32 %0, %1, %2" : "=v"(i3) : "v"(hi[2]), "v"(hi[3]));
    i32x4 w = {i0, i1, i2, i3};
    return __builtin_bit_cast(bf16x8, w);
}

__global__ __launch_bounds__(TPB, 3)
void atomwise_mfma_kernel(const float* __restrict__ x,
                          const float* __restrict__ W1,
                          const float* __restrict__ b1,
                          const float* __restrict__ W2,
                          const float* __restrict__ b2,
                          const int*   __restrict__ idx_m,
                          float*       __restrict__ out,
                          int n_atoms)
{
    __shared__ short w1t[N_HID][N_IN + LDS_PAD];   // W1^T in bf16

    const int tid = threadIdx.x;

    // ---- one-time: stage W1^T (bf16) into LDS. W1 is [128][64] row-major ----
    for (int e = tid; e < N_IN * N_HID; e += TPB) {
        int k = e >> 6;     // 0..127
        int n = e & 63;     // 0..63
        w1t[n][k] = f2bf(W1[e]);
    }
    __syncthreads();

    const int lane = tid & 63;
    const int wv   = tid >> 6;
    const int l15  = lane & 15;
    const int g    = lane >> 4;     // 0..3 (k-group; also selects atoms g*4..g*4+3)

    // ---- hoist full B operand (W1^T fragments) into registers ----
    bf16x8 bfrag[4][4];             // [kt][nt]
    #pragma unroll
    for (int kt = 0; kt < 4; ++kt)
        #pragma unroll
        for (int nt = 0; nt < 4; ++nt) {
            const short* p = &w1t[nt * 16 + l15][kt * 32 + g * 8];
            bfrag[kt][nt] = *reinterpret_cast<const bf16x8*>(p);
        }

    // per-lane channel constants: channel = nt*16 + l15
    float bb[4], w2v[4];
    #pragma unroll
    for (int nt = 0; nt < 4; ++nt) {
        bb[nt]  = b1[nt * 16 + l15];
        w2v[nt] = W2[nt * 16 + l15];
    }
    const float b2v = b2[0];

    const int n_tiles = (n_atoms + 15) >> 4;
    const int n_waves = gridDim.x * WAVES_PER_BLOCK;
    int tile = blockIdx.x * WAVES_PER_BLOCK + wv;
    if (tile >= n_tiles) return;

    // ---- prologue: issue loads for first tile ----
    f32x4 xf[8];
    int mv;     // idx_m for atom (tile*16 + l15), clamped
    {
        int row  = tile * 16 + l15;
        int rowc = row < n_atoms ? row : (n_atoms - 1);
        const float* xp = x + (size_t)rowc * N_IN + g * 8;
        #pragma unroll
        for (int kt = 0; kt < 4; ++kt) {
            xf[2 * kt]     = *reinterpret_cast<const f32x4*>(xp + kt * 32);
            xf[2 * kt + 1] = *reinterpret_cast<const f32x4*>(xp + kt * 32 + 4);
        }
        mv = idx_m[rowc];
    }

    while (true) {
        // ---- convert current tile to bf16 A-fragments (waits vmcnt on its loads) ----
        bf16x8 a[4];
        #pragma unroll
        for (int kt = 0; kt < 4; ++kt)
            a[kt] = cvt8(xf[2 * kt], xf[2 * kt + 1]);

        // ---- prefetch next tile's x + idx into the (now free) buffers ----
        const int  ntile     = tile + n_waves;
        const bool have_next = ntile < n_tiles;
        int nmv = 0;
        if (have_next) {            // wave-uniform branch; loop backedge only from here
            int row  = ntile * 16 + l15;
            int rowc = row < n_atoms ? row : (n_atoms - 1);
            const float* xp = x + (size_t)rowc * N_IN + g * 8;
            #pragma unroll
            for (int kt = 0; kt < 4; ++kt) {
                xf[2 * kt]     = *reinterpret_cast<const f32x4*>(xp + kt * 32);
                xf[2 * kt + 1] = *reinterpret_cast<const f32x4*>(xp + kt * 32 + 4);
            }
            nmv = idx_m[rowc];
        }

        // ---- MFMA: 16 atoms x 64 hid over K=128 ----
        f32x4 acc[4] = {};          // [nt]; rows g*4+j, col l15
        #pragma unroll
        for (int kt = 0; kt < 4; ++kt)
            #pragma unroll
            for (int nt = 0; nt < 4; ++nt)
                acc[nt] = __builtin_amdgcn_mfma_f32_16x16x32_bf16(
                              a[kt], bfrag[kt][nt], acc[nt], 0, 0, 0);

        // ---- epilogue: bias + silu + dot(W2) — fast sigmoid via v_rcp ----
        float p[4];
        #pragma unroll
        for (int j = 0; j < 4; ++j) {
            float s = 0.f;
            #pragma unroll
            for (int nt = 0; nt < 4; ++nt) {
                float z = acc[nt][j] + bb[nt];
                float e = __expf(-z);
                float h = z * __builtin_amdgcn_rcpf(1.f + e);  // ~1ulp, fine at 0.125 tol
                s += h * w2v[nt];
            }
            p[j] = s;
        }

        // ---- segment reduction: fast path when the whole tile is one molecule ----
        const int  first = __shfl(mv, 0);
        const bool full  = (tile * 16 + 16) <= n_atoms;
        const bool uni   = full && (__all(mv == first) != 0);

        if (uni) {
            // all 16 atoms -> one molecule: one wave-wide sum, one atomic
            float s = p[0] + p[1] + p[2] + p[3];
            #pragma unroll
            for (int m = 1; m < 64; m <<= 1)
                s += __shfl_xor(s, m, 64);
            if (lane == 0)
                atomicAdd(&out[first], s + 16.0f * b2v);
        } else {
            // gather per-atom molecule ids before any further reduction
            int ia[4];
            #pragma unroll
            for (int j = 0; j < 4; ++j)
                ia[j] = __shfl(mv, g * 4 + j);
            // reduce across the 16 lanes sharing g (channels 0..63)
            #pragma unroll
            for (int m = 1; m < 16; m <<= 1) {
                #pragma unroll
                for (int j = 0; j < 4; ++j)
                    p[j] += __shfl_xor(p[j], m, 64);
            }
            if (l15 == 0) {
                #pragma unroll
                for (int j = 0; j < 4; ++j) {
                    int atom = tile * 16 + g * 4 + j;
                    if (atom < n_atoms)
                        atomicAdd(&out[ia[j]], p[j] + b2v);
                }
            }
        }

        if (!have_next) break;
        tile = ntile;
        mv   = nmv;
    }
}

extern "C" void kernel_launch(void* const* d_in, const int* in_sizes, int n_in,
                              void* d_out, int out_size, void* d_ws, size_t ws_size,
                              hipStream_t stream) {
    const float* x   = (const float*)d_in[0];
    const float* W1  = (const float*)d_in[1];
    const float* b1  = (const float*)d_in[2];
    const float* W2  = (const float*)d_in[3];
    const float* b2  = (const float*)d_in[4];
    const int*   idx = (const int*)d_in[5];
    // d_in[6] = num_segments (scalar) — equals out_size

    const int n_atoms = in_sizes[0] / N_IN;
    float* out = (float*)d_out;

    hipMemsetAsync(d_out, 0, (size_t)out_size * sizeof(float), stream);

    const int blocks = 2048;
    atomwise_mfma_kernel<<<blocks, TPB, 0, stream>>>(
        x, W1, b1, W2, b2, idx, out, n_atoms);
}